// Round 16
// baseline (442.744 us; speedup 1.0000x reference)
//
#include <hip/hip_runtime.h>

typedef __attribute__((ext_vector_type(4))) float f32x4;
typedef __attribute__((ext_vector_type(8))) __bf16 bf16x8;

__device__ __forceinline__ unsigned short f2b(float f){
  union { float f; unsigned int u; } v; v.f = f;
  unsigned int r = v.u + 0x7FFFu + ((v.u >> 16) & 1u);
  return (unsigned short)(r >> 16);
}
__device__ __forceinline__ float b2f(unsigned short u){
  union { unsigned int u; float f; } v; v.u = ((unsigned int)u) << 16;
  return v.f;
}
__device__ __forceinline__ bool in_is_bf16(const void* g1){
  return ((const unsigned short*)g1)[0] == 0x3F80u;
}

#define GLD16(gp, lp) __builtin_amdgcn_global_load_lds( \
    (const __attribute__((address_space(1))) unsigned int*)(gp), \
    (__attribute__((address_space(3))) unsigned int*)(lp), 16, 0, 0)

// XCD-chunked bijective block swizzle (T1, m204). Requires nwg % 8 == 0.
__device__ __forceinline__ int xcd_swz(int L, int nwg){
  return (L & 7) * (nwg >> 3) + (L >> 3);
}

// ---------------- diagnostic fill ----------------------------------------
__global__ __launch_bounds__(256) void k_fill(float* p, long long n, float v){
  long long i = (long long)blockIdx.x*256 + threadIdx.x;
  long long stride = (long long)gridDim.x*256;
  for(; i < n; i += stride) p[i] = v;
}

struct SmallConv { const void* src[16]; int n[16]; int off[16]; };
struct TW4 { const void* s[4]; };

// ---- prep A: [small biases] + activation->bf16 (vectorized) + 4 transposes
template<bool SMALL>
__global__ __launch_bounds__(256) void k_prepA(SmallConv sc, float* bias,
    const void* act_in, unsigned short* act_out,
    TW4 tw, unsigned short* wdst, const void* g1f)
{
  __shared__ float tile[32][33];
  bool isb = in_is_bf16(g1f);
  int bi = blockIdx.x, tid = threadIdx.x;
  int base = SMALL ? 16 : 0;
  if(SMALL && bi < 16){
    const void* s = sc.src[bi];
    float* d = bias + sc.off[bi];
    int n = sc.n[bi];
    for(int j=tid;j<n;j+=256)
      d[j] = isb ? b2f(((const unsigned short*)s)[j]) : ((const float*)s)[j];
  } else if(bi < base + 2048){
    // one 8-elem group per thread: 2048 blocks x 256 thr x 8 = 4194304
    size_t g8 = ((size_t)(bi-base)*256 + tid) * 8;
    unsigned short tmp[8];
    if(isb){
      *(uint4*)tmp = *(const uint4*)((const unsigned short*)act_in + g8);
    } else {
      f32x4 a = *(const f32x4*)((const float*)act_in + g8);
      f32x4 b = *(const f32x4*)((const float*)act_in + g8 + 4);
      #pragma unroll
      for(int j=0;j<4;j++){ tmp[j] = f2b(a[j]); tmp[4+j] = f2b(b[j]); }
    }
    *(uint4*)(act_out + g8) = *(uint4*)tmp;
  } else {
    int r = bi - (base + 2048);
    int wi = r >> 10, rem = r & 1023;
    int c0 = (rem & 31)*32, r0 = (rem >> 5)*32;
    const void* src = tw.s[wi];
    unsigned short* dst = wdst + (size_t)wi*1048576;
    int tx = tid & 31, ty = tid >> 5;
    for(int rr=ty; rr<32; rr+=8){
      size_t o = (size_t)(r0+rr)*1024 + c0 + tx;
      tile[rr][tx] = isb ? b2f(((const unsigned short*)src)[o]) : ((const float*)src)[o];
    }
    __syncthreads();
    for(int cc=ty; cc<32; cc+=8)
      dst[(size_t)(c0+cc)*1024 + r0 + tx] = f2b(tile[tx][cc]);
  }
}

// ---- prep3: fc1^T + fc2^T ------------------------------------------------
__global__ __launch_bounds__(256) void k_prep3(
    const void* fc1, unsigned short* fc1t,
    const void* fc2, unsigned short* fc2t, const void* g1f)
{
  __shared__ float tile[32][33];
  bool isb = in_is_bf16(g1f);
  int bi = blockIdx.x, tid = threadIdx.x;
  const void* src; unsigned short* dst; int R, C, bx, by;
  if(bi < 4096){ src = fc1; dst = fc1t; R = 1024; C = 4096; bx = bi & 127; by = bi >> 7; }
  else { int r = bi - 4096; src = fc2; dst = fc2t; R = 4096; C = 1024; bx = r & 31; by = r >> 5; }
  int c0 = bx*32, r0 = by*32;
  int tx = tid & 31, ty = tid >> 5;
  for(int rr=ty; rr<32; rr+=8){
    size_t o = (size_t)(r0+rr)*C + c0 + tx;
    tile[rr][tx] = isb ? b2f(((const unsigned short*)src)[o]) : ((const float*)src)[o];
  }
  __syncthreads();
  for(int cc=ty; cc<32; cc+=8)
    dst[(size_t)(c0+cc)*R + r0 + tx] = f2b(tile[tx][cc]);
}

// ======== shared 256x256 8-phase core (T2 swizzle + T3/T4 + T5) ===========
#define STEP256(Ap, Bp, lda_, ldb_, m0_, n0_, kt, sg) { \
  int sb_ = (kt) & 1; \
  _Pragma("unroll") \
  for(int jj=0;jj<2;jj++){ \
    int c_ = (((sg)&1)*2 + jj)*512 + tid; \
    int s_ = c_ ^ ((c_ >> 3) & 7); \
    if(((sg) & 2) == 0) \
      GLD16((Ap) + (size_t)((m0_) + (s_>>3))*(lda_) + (kt)*64 + (s_&7)*8, \
            LA[sb_] + (size_t)c_*8); \
    else \
      GLD16((Bp) + (size_t)((n0_) + (s_>>3))*(ldb_) + (kt)*64 + (s_&7)*8, \
            LB[sb_] + (size_t)c_*8); \
  } }

#define GEMM256_BODY(Ap, Bp) \
  _Pragma("unroll") \
  for(int sg=0;sg<4;sg++) STEP256(Ap, Bp, lda, ldb, m0, n0, 0, sg); \
  if(NT > 1){ \
    _Pragma("unroll") \
    for(int sg=0;sg<4;sg++) STEP256(Ap, Bp, lda, ldb, m0, n0, 1, sg); \
    asm volatile("s_waitcnt vmcnt(8)" ::: "memory"); \
  } else { \
    asm volatile("s_waitcnt vmcnt(0)" ::: "memory"); \
  } \
  __builtin_amdgcn_s_barrier(); \
  for(int kt = 0; kt < NT; ++kt){ \
    int cur = kt & 1; \
    _Pragma("unroll") \
    for(int q=0;q<4;q++){ \
      bf16x8 afr[2][2], bfr[4][2]; \
      _Pragma("unroll") \
      for(int i=0;i<2;i++){ \
        int row = wr*128 + (2*q+i)*16 + lr; \
        _Pragma("unroll") \
        for(int ks=0;ks<2;ks++){ \
          int ch = (row*8 + ks*4 + lg) ^ (row & 7); \
          afr[i][ks] = *(const bf16x8*)(LA[cur] + (size_t)ch*8); \
        } \
      } \
      _Pragma("unroll") \
      for(int n=0;n<4;n++){ \
        int row = wc*64 + n*16 + lr; \
        _Pragma("unroll") \
        for(int ks=0;ks<2;ks++){ \
          int ch = (row*8 + ks*4 + lg) ^ (row & 7); \
          bfr[n][ks] = *(const bf16x8*)(LB[cur] + (size_t)ch*8); \
        } \
      } \
      int P = kt*4 + q; \
      if(P >= 3){ \
        int k2 = (P+5) >> 2, sg = (P+5) & 3; \
        if(k2 < NT) STEP256(Ap, Bp, lda, ldb, m0, n0, k2, sg); \
      } \
      __builtin_amdgcn_s_barrier(); \
      __builtin_amdgcn_s_setprio(1); \
      _Pragma("unroll") \
      for(int i=0;i<2;i++) \
        _Pragma("unroll") \
        for(int n=0;n<4;n++) \
          _Pragma("unroll") \
          for(int ks=0;ks<2;ks++) \
            acc[2*q+i][n] = __builtin_amdgcn_mfma_f32_16x16x32_bf16( \
                afr[i][ks], bfr[n][ks], acc[2*q+i][n], 0,0,0); \
      __builtin_amdgcn_s_setprio(0); \
      __builtin_amdgcn_s_barrier(); \
    } \
    if(kt + 1 < NT){ \
      if(kt + 2 < NT) asm volatile("s_waitcnt vmcnt(2)" ::: "memory"); \
      else            asm volatile("s_waitcnt vmcnt(0)" ::: "memory"); \
      __builtin_amdgcn_s_barrier(); \
    } \
  }

// ------- plain 256x256 8-phase GEMM ---------------------------------------
template<int EPI>
__global__ __launch_bounds__(512) void k_gemm256(
    const unsigned short* __restrict__ A, int lda,
    const unsigned short* __restrict__ Bt, int ldb,
    void* __restrict__ Cout, int ldc,
    const float* __restrict__ bias, const unsigned short* __restrict__ resid, int K)
{
  __shared__ __align__(16) unsigned short LA[2][256*64];
  __shared__ __align__(16) unsigned short LB[2][256*64];
  int tid = threadIdx.x;
  int lane = tid & 63;
  int lr = lane & 15, lg = lane >> 4;
  int w = tid >> 6, wr = w >> 2, wc = w & 3;
  int nwg = gridDim.x * gridDim.y;
  int v = xcd_swz(blockIdx.y * gridDim.x + blockIdx.x, nwg);
  int bx = v % gridDim.x, by = v / gridDim.x;
  int m0 = by * 256, n0 = bx * 256;
  int NT = K >> 6;

  f32x4 acc[8][4];
  #pragma unroll
  for(int m=0;m<8;m++)
    #pragma unroll
    for(int n=0;n<4;n++) acc[m][n] = (f32x4){0.f,0.f,0.f,0.f};

  GEMM256_BODY(A, Bt)

  #pragma unroll
  for(int m=0;m<8;m++){
    #pragma unroll
    for(int n=0;n<4;n++){
      int col = n0 + wc*64 + n*16 + lr;
      float bb = bias[col];
      #pragma unroll
      for(int r=0;r<4;r++){
        int row = m0 + wr*128 + m*16 + lg*4 + r;
        size_t o = (size_t)row*ldc + col;
        float v2 = acc[m][n][r] + bb;
        if constexpr (EPI == 0){
          ((unsigned short*)Cout)[o] = f2b(v2);
        } else if constexpr (EPI == 1){
          ((unsigned short*)Cout)[o] = f2b(v2 > 0.f ? v2 : 0.f);
        } else if constexpr (EPI == 2){
          ((unsigned short*)Cout)[o] = f2b(v2 + b2f(resid[o]));
        } else {
          ((float*)Cout)[o] = v2 + b2f(resid[o]);
        }
      }
    }
  }
}

// ------- 256x256 8-phase split GEMM: per-1024-col outputs; TSLOT -> Vt ----
template<int TSLOT>
__global__ __launch_bounds__(512) void k_gemmsplit256(
    const unsigned short* __restrict__ A,
    const unsigned short* __restrict__ A2, int lda,
    const unsigned short* __restrict__ Bt, int ldb,
    unsigned short* __restrict__ C0, unsigned short* __restrict__ C1,
    unsigned short* __restrict__ C2,
    const float* __restrict__ bias, int K)
{
  __shared__ __align__(16) unsigned short LA[2][256*64];
  __shared__ __align__(16) unsigned short LB[2][256*64];
  int tid = threadIdx.x;
  int lane = tid & 63;
  int lr = lane & 15, lg = lane >> 4;
  int w = tid >> 6, wr = w >> 2, wc = w & 3;
  int nwg = gridDim.x * gridDim.y;
  int v = xcd_swz(blockIdx.y * gridDim.x + blockIdx.x, nwg);
  int bx = v % gridDim.x, by = v / gridDim.x;
  int m0 = by * 256, n0 = bx * 256;
  int NT = K >> 6;
  int slot = bx >> 2;
  unsigned short* Cs = slot == 0 ? C0 : (slot == 1 ? C1 : C2);
  const unsigned short* Au = (slot == 0) ? A2 : A;
  int nl0 = (bx & 3) * 256;

  f32x4 acc[8][4];
  #pragma unroll
  for(int m=0;m<8;m++)
    #pragma unroll
    for(int n=0;n<4;n++) acc[m][n] = (f32x4){0.f,0.f,0.f,0.f};

  GEMM256_BODY(Au, Bt)

  if(slot != TSLOT){
    #pragma unroll
    for(int m=0;m<8;m++){
      #pragma unroll
      for(int n=0;n<4;n++){
        int coll = nl0 + wc*64 + n*16 + lr;
        float bb = bias[bx*256 + wc*64 + n*16 + lr];
        #pragma unroll
        for(int r=0;r<4;r++){
          int row = m0 + wr*128 + m*16 + lg*4 + r;
          Cs[(size_t)row*1024 + coll] = f2b(acc[m][n][r] + bb);
        }
      }
    }
  } else {
    #pragma unroll
    for(int m=0;m<8;m++){
      #pragma unroll
      for(int n=0;n<4;n++){
        int vcol = nl0 + wc*64 + n*16 + lr;
        float bb = bias[bx*256 + wc*64 + n*16 + lr];
        int rowb = m0 + wr*128 + m*16 + lg*4;
        int z = (rowb >> 9)*16 + (vcol >> 6);
        unsigned short tmp[4];
        #pragma unroll
        for(int r=0;r<4;r++) tmp[r] = f2b(acc[m][n][r] + bb);
        *(ushort4*)&Cs[((size_t)(z*64 + (vcol & 63)))*512 + (rowb & 511)] = *(ushort4*)tmp;
      }
    }
  }
}

// ------- 128x64 GEMM, double-buffered, XCD-swizzled -----------------------
template<int EPI>
__global__ __launch_bounds__(256) void k_gemm64(
    const unsigned short* __restrict__ A, int lda,
    const unsigned short* __restrict__ Bt, int ldb,
    void* __restrict__ Cout, int ldc,
    const float* __restrict__ bias, const unsigned short* __restrict__ resid, int K)
{
  __shared__ unsigned short As[2][128*32];
  __shared__ unsigned short Bs[2][64*32];
  int tid = threadIdx.x, lane = tid & 63, w = tid >> 6;
  int lr = lane & 15, lg = lane >> 4;
  int nwg = gridDim.x * gridDim.y;
  int v = xcd_swz(blockIdx.y * gridDim.x + blockIdx.x, nwg);
  int bx = v % gridDim.x, by = v / gridDim.x;
  int m0 = by * 128, n0 = bx * 64;

  f32x4 acc[2][4];
  #pragma unroll
  for(int m=0;m<2;m++)
    #pragma unroll
    for(int n=0;n<4;n++) acc[m][n] = (f32x4){0.f,0.f,0.f,0.f};

  #pragma unroll
  for(int j=0;j<2;j++){
    int idx = j*256 + tid;
    GLD16(A + (size_t)(m0 + (idx>>2))*lda + (idx&3)*8,
          As[0] + (size_t)(j*256 + (tid & 192))*8);
  }
  GLD16(Bt + (size_t)(n0 + (tid>>2))*ldb + (tid&3)*8,
        Bs[0] + (size_t)(tid & 192)*8);
  __syncthreads();

  int cur = 0;
  for(int k0 = 0; k0 < K; k0 += 32){
    if(k0 + 32 < K){
      #pragma unroll
      for(int j=0;j<2;j++){
        int idx = j*256 + tid;
        GLD16(A + (size_t)(m0 + (idx>>2))*lda + k0 + 32 + (idx&3)*8,
              As[cur^1] + (size_t)(j*256 + (tid & 192))*8);
      }
      GLD16(Bt + (size_t)(n0 + (tid>>2))*ldb + k0 + 32 + (tid&3)*8,
            Bs[cur^1] + (size_t)(tid & 192)*8);
    }
    bf16x8 a[2], bf[4];
    #pragma unroll
    for(int m=0;m<2;m++) a[m] = *(const bf16x8*)&As[cur][(w*32 + m*16 + lr)*32 + lg*8];
    #pragma unroll
    for(int n=0;n<4;n++) bf[n] = *(const bf16x8*)&Bs[cur][(n*16 + lr)*32 + lg*8];
    #pragma unroll
    for(int m=0;m<2;m++)
      #pragma unroll
      for(int n=0;n<4;n++)
        acc[m][n] = __builtin_amdgcn_mfma_f32_16x16x32_bf16(a[m], bf[n], acc[m][n], 0,0,0);
    __syncthreads();
    cur ^= 1;
  }

  #pragma unroll
  for(int m=0;m<2;m++){
    #pragma unroll
    for(int n=0;n<4;n++){
      int col = n0 + n*16 + lr;
      float bb = bias[col];
      #pragma unroll
      for(int r=0;r<4;r++){
        int row = m0 + w*32 + m*16 + lg*4 + r;
        size_t o = (size_t)row*ldc + col;
        float v2 = acc[m][n][r] + bb;
        if constexpr (EPI == 0){
          ((unsigned short*)Cout)[o] = f2b(v2);
        } else if constexpr (EPI == 1){
          ((unsigned short*)Cout)[o] = f2b(v2 > 0.f ? v2 : 0.f);
        } else if constexpr (EPI == 2){
          ((unsigned short*)Cout)[o] = f2b(v2 + b2f(resid[o]));
        } else {
          ((float*)Cout)[o] = v2 + b2f(resid[o]);
        }
      }
    }
  }
}

// -- fused attention (XCD-swizzled), K and V staged via swizzled LDS -------
// Grid must be (16,16,8). C may alias Q (Q consumed into regs first).
template<bool CAUSAL>
__global__ __launch_bounds__(256) void k_attnf(
    const unsigned short* Q,
    const unsigned short* __restrict__ Km,
    const unsigned short* __restrict__ Vt,
    float* __restrict__ P,
    unsigned short* C)
{
  int tid = threadIdx.x, lane = tid & 63, w = tid >> 6;
  int lr = lane & 15, lg = lane >> 4;
  int L = (blockIdx.z * 16 + blockIdx.y) * 16 + blockIdx.x;
  int v = xcd_swz(L, 2048);
  int s0 = (v & 15) * 32;
  int h = (v >> 4) & 15;
  int b = v >> 8;
  int z = b*16 + h;
  const unsigned short* Qb = Q + ((size_t)(b*512 + s0))*1024 + h*64;
  const unsigned short* Kb = Km + ((size_t)(b*512))*1024 + h*64;
  const unsigned short* Vb0 = Vt + (size_t)z*64*512;
  float* Pb = P + ((size_t)(z*512 + s0))*512;

  __shared__ unsigned short P_lds[32*520];     // aliased: first 16 KB = K-stage
  __shared__ __align__(16) unsigned short Vs[2][64*64];  // V chunks (64 k each)
  __shared__ float redm[32][4];
  __shared__ float reds[32][4];
  unsigned short* Ks = P_lds;

  // prefetch V chunk 0 (completes under QK^T's vmcnt(0) waits)
  #pragma unroll
  for(int j=0;j<2;j++){
    int g = j*256 + tid;
    int s = g ^ ((g>>3)&7);
    GLD16(Vb0 + (size_t)(s>>3)*512 + (s&7)*8, Vs[0] + (size_t)g*8);
  }

  bf16x8 aq[2][2];
  #pragma unroll
  for(int m=0;m<2;m++)
    #pragma unroll
    for(int kk=0;kk<2;kk++)
      aq[m][kk] = *(const bf16x8*)(Qb + (size_t)(m*16 + lr)*1024 + kk*32 + lg*8);

  f32x4 sc[2][8];
  #pragma unroll
  for(int m=0;m<2;m++)
    #pragma unroll
    for(int cb=0;cb<8;cb++) sc[m][cb] = (f32x4){0.f,0.f,0.f,0.f};

  // QK^T in 4 chunks of 128 K-columns, K staged in LDS
  for(int cc2 = 0; cc2 < 4; ++cc2){
    #pragma unroll
    for(int j=0;j<4;j++){
      int g = j*256 + tid;
      int s = g ^ ((g >> 3) & 7);
      GLD16(Kb + (size_t)(cc2*128 + (s>>3))*1024 + (s&7)*8,
            Ks + (size_t)g*8);
    }
    asm volatile("s_waitcnt vmcnt(0)" ::: "memory");
    __syncthreads();
    #pragma unroll
    for(int cbl=0;cbl<2;cbl++){
      int cb = cc2*2 + cbl;
      int col_l = cbl*64 + w*16 + lr;
      #pragma unroll
      for(int kk=0; kk<2; kk++){
        int ch = (col_l*8 + kk*4 + lg) ^ (col_l & 7);
        bf16x8 bq = *(const bf16x8*)(Ks + (size_t)ch*8);
        #pragma unroll
        for(int m=0;m<2;m++)
          sc[m][cb] = __builtin_amdgcn_mfma_f32_16x16x32_bf16(aq[m][kk], bq, sc[m][cb], 0,0,0);
      }
    }
    __syncthreads();
  }

  #pragma unroll
  for(int m=0;m<2;m++)
    #pragma unroll
    for(int cb=0;cb<8;cb++)
      #pragma unroll
      for(int r=0;r<4;r++){
        int row_l = m*16 + lg*4 + r;
        int col = cb*64 + w*16 + lr;
        float sv = sc[m][cb][r] * 0.125f;
        if(CAUSAL && col > s0 + row_l) sv = -1e9f;
        sc[m][cb][r] = sv;
      }

  float gmax[2][4];
  #pragma unroll
  for(int m=0;m<2;m++)
    #pragma unroll
    for(int r=0;r<4;r++){
      float pm = -1e30f;
      #pragma unroll
      for(int cb=0;cb<8;cb++) pm = fmaxf(pm, sc[m][cb][r]);
      #pragma unroll
      for(int off=1; off<16; off<<=1) pm = fmaxf(pm, __shfl_xor(pm, off));
      if(lr == 0) redm[m*16 + lg*4 + r][w] = pm;
    }
  __syncthreads();
  #pragma unroll
  for(int m=0;m<2;m++)
    #pragma unroll
    for(int r=0;r<4;r++){
      int row_l = m*16 + lg*4 + r;
      gmax[m][r] = fmaxf(fmaxf(redm[row_l][0], redm[row_l][1]),
                         fmaxf(redm[row_l][2], redm[row_l][3]));
    }
  #pragma unroll
  for(int m=0;m<2;m++)
    #pragma unroll
    for(int r=0;r<4;r++){
      float ps = 0.f;
      #pragma unroll
      for(int cb=0;cb<8;cb++){
        float e = __expf(sc[m][cb][r] - gmax[m][r]);
        sc[m][cb][r] = e;
        ps += e;
      }
      #pragma unroll
      for(int off=1; off<16; off<<=1) ps += __shfl_xor(ps, off);
      if(lr == 0) reds[m*16 + lg*4 + r][w] = ps;
    }
  __syncthreads();
  #pragma unroll
  for(int m=0;m<2;m++)
    #pragma unroll
    for(int r=0;r<4;r++){
      int row_l = m*16 + lg*4 + r;
      float inv = 1.f / (reds[row_l][0] + reds[row_l][1] + reds[row_l][2] + reds[row_l][3]);
      #pragma unroll
      for(int cb=0;cb<8;cb++){
        int col = cb*64 + w*16 + lr;
        float p = sc[m][cb][r] * inv;
        Pb[(size_t)row_l*512 + col] = p;
        P_lds[row_l*520 + col] = f2b(p);
      }
    }
  __syncthreads();

  // PV with double-buffered V chunks (8 chunks of 64 k)
  int vrow = w*16 + lr;
  f32x4 pacc[2];
  pacc[0] = (f32x4){0.f,0.f,0.f,0.f};
  pacc[1] = (f32x4){0.f,0.f,0.f,0.f};
  for(int c = 0; c < 8; ++c){
    if(c + 1 < 8){
      #pragma unroll
      for(int j=0;j<2;j++){
        int g = j*256 + tid;
        int s = g ^ ((g>>3)&7);
        GLD16(Vb0 + (size_t)(s>>3)*512 + (c+1)*64 + (s&7)*8,
              Vs[(c+1)&1] + (size_t)g*8);
      }
    }
    #pragma unroll
    for(int kkl=0;kkl<2;kkl++){
      int q = kkl*4 + lg;
      int ch = (vrow*8 + q) ^ (vrow & 7);
      bf16x8 bfrag = *(const bf16x8*)(Vs[c&1] + (size_t)ch*8);
      #pragma unroll
      for(int m=0;m<2;m++){
        bf16x8 afrag = *(const bf16x8*)&P_lds[(m*16 + lr)*520 + (c*2+kkl)*32 + lg*8];
        pacc[m] = __builtin_amdgcn_mfma_f32_16x16x32_bf16(afrag, bfrag, pacc[m], 0,0,0);
      }
    }
    asm volatile("s_waitcnt vmcnt(0) lgkmcnt(0)" ::: "memory");
    __builtin_amdgcn_s_barrier();
  }
  #pragma unroll
  for(int m=0;m<2;m++)
    #pragma unroll
    for(int r=0;r<4;r++)
      C[((size_t)(b*512 + s0 + m*16 + lg*4 + r))*1024 + h*64 + w*16 + lr] = f2b(pacc[m][r]);
}

// ------- LayerNorm over D=1024; templated in/out dtype (0=bf16,1=f32) -----
template<int F32IN, int F32OUT>
__global__ __launch_bounds__(256) void k_ln(const void* __restrict__ in,
    const float* __restrict__ g, const float* __restrict__ be,
    void* __restrict__ out)
{
  int row = blockIdx.x, tid = threadIdx.x;
  float v[4];
  if constexpr (F32IN){
    f32x4 u = *(const f32x4*)((const float*)in + (size_t)row*1024 + tid*4);
    v[0]=u[0]; v[1]=u[1]; v[2]=u[2]; v[3]=u[3];
  } else {
    uint2 u = *(const uint2*)((const unsigned short*)in + (size_t)row*1024 + tid*4);
    v[0] = b2f(u.x & 0xFFFF); v[1] = b2f(u.x >> 16);
    v[2] = b2f(u.y & 0xFFFF); v[3] = b2f(u.y >> 16);
  }
  float s = v[0]+v[1]+v[2]+v[3];
  float s2 = v[0]*v[0]+v[1]*v[1]+v[2]*v[2]+v[3]*v[3];
  #pragma unroll
  for(int off=1; off<64; off<<=1){ s += __shfl_xor(s, off); s2 += __shfl_xor(s2, off); }
  __shared__ float red[2][4];
  int w = tid >> 6;
  if((tid & 63) == 0){ red[0][w] = s; red[1][w] = s2; }
  __syncthreads();
  s  = red[0][0]+red[0][1]+red[0][2]+red[0][3];
  s2 = red[1][0]+red[1][1]+red[1][2]+red[1][3];
  float mu = s * (1.f/1024.f);
  float var = s2 * (1.f/1024.f) - mu*mu;
  float rstd = rsqrtf(var + 1e-6f);
  int c = tid*4;
  float y0 = (v[0]-mu)*rstd*g[c+0] + be[c+0];
  float y1 = (v[1]-mu)*rstd*g[c+1] + be[c+1];
  float y2 = (v[2]-mu)*rstd*g[c+2] + be[c+2];
  float y3 = (v[3]-mu)*rstd*g[c+3] + be[c+3];
  if constexpr (F32OUT){
    f32x4 o = {y0, y1, y2, y3};
    *(f32x4*)((float*)out + (size_t)row*1024 + c) = o;
  } else {
    unsigned int o0 = (unsigned int)f2b(y0) | ((unsigned int)f2b(y1) << 16);
    unsigned int o1 = (unsigned int)f2b(y2) | ((unsigned int)f2b(y3) << 16);
    *(uint2*)((unsigned short*)out + (size_t)row*1024 + c) = make_uint2(o0, o1);
  }
}

// ---------------- launch ---------------------------------------------------
extern "C" void kernel_launch(void* const* d_in, const int* in_sizes, int n_in,
                              void* d_out, int out_size, void* d_ws, size_t ws_size,
                              hipStream_t stream)
{
  float* out0 = (float*)d_out;

  static const int exp_sizes[29] = {
    4194304, 4194304, 262144,
    1048576, 1024, 1048576, 1024, 1048576, 1024, 1048576, 1024,
    1048576, 1024, 1048576, 1024, 1048576, 1024, 1048576, 1024,
    1024, 1024, 1024, 1024, 1024, 1024,
    4194304, 4096, 4194304, 1024 };
  bool ok = (n_in == 29);
  if(ok) for(int i=0;i<29;i++) if(in_sizes[i] != exp_sizes[i]) { ok = false; break; }
  if(!ok){
    k_fill<<<2048,256,0,stream>>>(out0, (long long)out_size, 100.0f);
    return;
  }
  size_t nslots = ws_size > 131072 ? (ws_size - 131072) / 8388608 : 0;
  if(nslots < 5){
    k_fill<<<2048,256,0,stream>>>(out0, (long long)out_size, 200.0f);
    return;
  }
  bool bigws = nslots >= 9;

  const void* g1f = d_in[19];
  char* ws = (char*)d_ws;
  float* bias = (float*)(ws);
  unsigned short* SL[9];
  for(int i=0;i<9;i++) SL[i] = (unsigned short*)(ws + 131072 + (size_t)i*8388608);

  float* P1 = out0 + 4194304;
  float* P2 = P1 + 33554432;
  unsigned short* Q2buf = (unsigned short*)out0;

  SmallConv scv;
  const int si[16] = {4,6,8,10,12,14,16,18,19,20,21,22,23,24,26,28};
  const int sn[16] = {1024,1024,1024,1024,1024,1024,1024,1024,
                      1024,1024,1024,1024,1024,1024,4096,1024};
  const int so[16] = {0,1024,2048,3072,4096,5120,6144,7168,
                      8192,9216,10240,11264,12288,13312,14336,18432};
  for(int i=0;i<16;i++){ scv.src[i]=d_in[si[i]]; scv.n[i]=sn[i]; scv.off[i]=so[i]; }

  // ---- MHA1 (self, causal) ----
  {
    TW4 tw{}; tw.s[0]=d_in[3]; tw.s[1]=d_in[5]; tw.s[2]=d_in[7]; tw.s[3]=d_in[9];
    k_prepA<true><<<6160,256,0,stream>>>(scv, bias, d_in[0], SL[0], tw, SL[1], g1f);
  }
  k_gemmsplit256<2><<<dim3(12,16),512,0,stream>>>(SL[0], SL[0],1024, SL[1],1024,
                                                  SL[2], SL[3], SL[4], bias+0, 1024);
  k_attnf<true><<<dim3(16,16,8),256,0,stream>>>(SL[2], SL[3], SL[4], P1, SL[2]);
  k_gemm64<2><<<dim3(16,32),256,0,stream>>>(SL[2],1024, SL[1]+3145728,1024,
                                            SL[3],1024, bias+3072, SL[0], 1024);
  k_ln<0,0><<<4096,256,0,stream>>>(SL[3], bias+8192, bias+9216, SL[4]);

  // ---- MHA2 (cross, unmasked): merged Q2/K2/V2 ----
  {
    TW4 tw{}; tw.s[0]=d_in[11]; tw.s[1]=d_in[13]; tw.s[2]=d_in[15]; tw.s[3]=d_in[17];
    k_prepA<false><<<6144,256,0,stream>>>(scv, bias, d_in[1], SL[0], tw, SL[1], g1f);
  }
  k_gemmsplit256<2><<<dim3(12,16),512,0,stream>>>(SL[0], SL[4],1024, SL[1],1024,
                                                  Q2buf, SL[2], SL[3], bias+4096, 1024);
  k_attnf<false><<<dim3(16,16,8),256,0,stream>>>(Q2buf, SL[2], SL[3], P2, SL[0]);
  k_gemm64<2><<<dim3(16,32),256,0,stream>>>(SL[0],1024, SL[1]+3145728,1024,
                                            SL[2],1024, bias+7168, SL[4], 1024);
  k_ln<0,0><<<4096,256,0,stream>>>(SL[2], bias+10240, bias+11264, SL[3]);

  // ---- FFN ----
  k_prep3<<<8192,256,0,stream>>>(d_in[25], SL[4], d_in[27], SL[0], g1f);
  if(bigws){
    unsigned short* H = SL[5];
    k_gemm256<1><<<dim3(16,16),512,0,stream>>>(SL[3],1024, SL[4],1024, H,4096,
                                               bias+14336, nullptr, 1024);
    k_gemm64<3><<<dim3(16,32),256,0,stream>>>(H,4096, SL[0],4096, out0,1024, bias+18432, SL[3], 4096);
    k_ln<1,1><<<4096,256,0,stream>>>(out0, bias+12288, bias+13312, out0);
  } else {
    unsigned short* H = SL[1];
    for(int c=0;c<2;c++){
      unsigned short* arow = SL[3] + (size_t)c*2097152;
      float* orow = out0 + (size_t)c*2097152;
      k_gemm256<1><<<dim3(16,8),512,0,stream>>>(arow,1024, SL[4],1024, H,4096,
                                                bias+14336, nullptr, 1024);
      k_gemm64<3><<<dim3(16,16),256,0,stream>>>(H,4096, SL[0],4096, orow,1024, bias+18432, arow, 4096);
      k_ln<1,1><<<2048,256,0,stream>>>(orow, bias+12288, bias+13312, orow);
    }
  }
}

// Round 17
// 430.578 us; speedup vs baseline: 1.0283x; 1.0283x over previous
//
#include <hip/hip_runtime.h>

typedef __attribute__((ext_vector_type(4))) float f32x4;
typedef __attribute__((ext_vector_type(8))) __bf16 bf16x8;

__device__ __forceinline__ unsigned short f2b(float f){
  union { float f; unsigned int u; } v; v.f = f;
  unsigned int r = v.u + 0x7FFFu + ((v.u >> 16) & 1u);
  return (unsigned short)(r >> 16);
}
__device__ __forceinline__ float b2f(unsigned short u){
  union { unsigned int u; float f; } v; v.u = ((unsigned int)u) << 16;
  return v.f;
}
__device__ __forceinline__ bool in_is_bf16(const void* g1){
  return ((const unsigned short*)g1)[0] == 0x3F80u;
}

#define GLD16(gp, lp) __builtin_amdgcn_global_load_lds( \
    (const __attribute__((address_space(1))) unsigned int*)(gp), \
    (__attribute__((address_space(3))) unsigned int*)(lp), 16, 0, 0)

// XCD-chunked bijective block swizzle (T1, m204). Requires nwg % 8 == 0.
__device__ __forceinline__ int xcd_swz(int L, int nwg){
  return (L & 7) * (nwg >> 3) + (L >> 3);
}

// ---------------- diagnostic fill ----------------------------------------
__global__ __launch_bounds__(256) void k_fill(float* p, long long n, float v){
  long long i = (long long)blockIdx.x*256 + threadIdx.x;
  long long stride = (long long)gridDim.x*256;
  for(; i < n; i += stride) p[i] = v;
}

struct SmallConv { const void* src[16]; int n[16]; int off[16]; };
struct TW4 { const void* s[4]; };

// ---- prep A: [small biases] + activation->bf16 (vectorized) + 4 transposes
template<bool SMALL>
__global__ __launch_bounds__(256) void k_prepA(SmallConv sc, float* bias,
    const void* act_in, unsigned short* act_out,
    TW4 tw, unsigned short* wdst, const void* g1f)
{
  __shared__ float tile[32][33];
  bool isb = in_is_bf16(g1f);
  int bi = blockIdx.x, tid = threadIdx.x;
  int base = SMALL ? 16 : 0;
  if(SMALL && bi < 16){
    const void* s = sc.src[bi];
    float* d = bias + sc.off[bi];
    int n = sc.n[bi];
    for(int j=tid;j<n;j+=256)
      d[j] = isb ? b2f(((const unsigned short*)s)[j]) : ((const float*)s)[j];
  } else if(bi < base + 2048){
    size_t g8 = ((size_t)(bi-base)*256 + tid) * 8;
    unsigned short tmp[8];
    if(isb){
      *(uint4*)tmp = *(const uint4*)((const unsigned short*)act_in + g8);
    } else {
      f32x4 a = *(const f32x4*)((const float*)act_in + g8);
      f32x4 b = *(const f32x4*)((const float*)act_in + g8 + 4);
      #pragma unroll
      for(int j=0;j<4;j++){ tmp[j] = f2b(a[j]); tmp[4+j] = f2b(b[j]); }
    }
    *(uint4*)(act_out + g8) = *(uint4*)tmp;
  } else {
    int r = bi - (base + 2048);
    int wi = r >> 10, rem = r & 1023;
    int c0 = (rem & 31)*32, r0 = (rem >> 5)*32;
    const void* src = tw.s[wi];
    unsigned short* dst = wdst + (size_t)wi*1048576;
    int tx = tid & 31, ty = tid >> 5;
    for(int rr=ty; rr<32; rr+=8){
      size_t o = (size_t)(r0+rr)*1024 + c0 + tx;
      tile[rr][tx] = isb ? b2f(((const unsigned short*)src)[o]) : ((const float*)src)[o];
    }
    __syncthreads();
    for(int cc=ty; cc<32; cc+=8)
      dst[(size_t)(c0+cc)*1024 + r0 + tx] = f2b(tile[tx][cc]);
  }
}

// ---- prep3: fc1^T + fc2^T ------------------------------------------------
__global__ __launch_bounds__(256) void k_prep3(
    const void* fc1, unsigned short* fc1t,
    const void* fc2, unsigned short* fc2t, const void* g1f)
{
  __shared__ float tile[32][33];
  bool isb = in_is_bf16(g1f);
  int bi = blockIdx.x, tid = threadIdx.x;
  const void* src; unsigned short* dst; int R, C, bx, by;
  if(bi < 4096){ src = fc1; dst = fc1t; R = 1024; C = 4096; bx = bi & 127; by = bi >> 7; }
  else { int r = bi - 4096; src = fc2; dst = fc2t; R = 4096; C = 1024; bx = r & 31; by = r >> 5; }
  int c0 = bx*32, r0 = by*32;
  int tx = tid & 31, ty = tid >> 5;
  for(int rr=ty; rr<32; rr+=8){
    size_t o = (size_t)(r0+rr)*C + c0 + tx;
    tile[rr][tx] = isb ? b2f(((const unsigned short*)src)[o]) : ((const float*)src)[o];
  }
  __syncthreads();
  for(int cc=ty; cc<32; cc+=8)
    dst[(size_t)(c0+cc)*R + r0 + tx] = f2b(tile[tx][cc]);
}

// ======== shared 256x256 8-phase core (T2 swizzle + T3/T4 + T5) ===========
#define STEP256(Ap, Bp, lda_, ldb_, m0_, n0_, kt, sg) { \
  int sb_ = (kt) & 1; \
  _Pragma("unroll") \
  for(int jj=0;jj<2;jj++){ \
    int c_ = (((sg)&1)*2 + jj)*512 + tid; \
    int s_ = c_ ^ ((c_ >> 3) & 7); \
    if(((sg) & 2) == 0) \
      GLD16((Ap) + (size_t)((m0_) + (s_>>3))*(lda_) + (kt)*64 + (s_&7)*8, \
            LA[sb_] + (size_t)c_*8); \
    else \
      GLD16((Bp) + (size_t)((n0_) + (s_>>3))*(ldb_) + (kt)*64 + (s_&7)*8, \
            LB[sb_] + (size_t)c_*8); \
  } }

#define GEMM256_BODY(Ap, Bp) \
  _Pragma("unroll") \
  for(int sg=0;sg<4;sg++) STEP256(Ap, Bp, lda, ldb, m0, n0, 0, sg); \
  if(NT > 1){ \
    _Pragma("unroll") \
    for(int sg=0;sg<4;sg++) STEP256(Ap, Bp, lda, ldb, m0, n0, 1, sg); \
    asm volatile("s_waitcnt vmcnt(8)" ::: "memory"); \
  } else { \
    asm volatile("s_waitcnt vmcnt(0)" ::: "memory"); \
  } \
  __builtin_amdgcn_s_barrier(); \
  for(int kt = 0; kt < NT; ++kt){ \
    int cur = kt & 1; \
    _Pragma("unroll") \
    for(int q=0;q<4;q++){ \
      bf16x8 afr[2][2], bfr[4][2]; \
      _Pragma("unroll") \
      for(int i=0;i<2;i++){ \
        int row = wr*128 + (2*q+i)*16 + lr; \
        _Pragma("unroll") \
        for(int ks=0;ks<2;ks++){ \
          int ch = (row*8 + ks*4 + lg) ^ (row & 7); \
          afr[i][ks] = *(const bf16x8*)(LA[cur] + (size_t)ch*8); \
        } \
      } \
      _Pragma("unroll") \
      for(int n=0;n<4;n++){ \
        int row = wc*64 + n*16 + lr; \
        _Pragma("unroll") \
        for(int ks=0;ks<2;ks++){ \
          int ch = (row*8 + ks*4 + lg) ^ (row & 7); \
          bfr[n][ks] = *(const bf16x8*)(LB[cur] + (size_t)ch*8); \
        } \
      } \
      int P = kt*4 + q; \
      if(P >= 3){ \
        int k2 = (P+5) >> 2, sg = (P+5) & 3; \
        if(k2 < NT) STEP256(Ap, Bp, lda, ldb, m0, n0, k2, sg); \
      } \
      __builtin_amdgcn_s_barrier(); \
      __builtin_amdgcn_s_setprio(1); \
      _Pragma("unroll") \
      for(int i=0;i<2;i++) \
        _Pragma("unroll") \
        for(int n=0;n<4;n++) \
          _Pragma("unroll") \
          for(int ks=0;ks<2;ks++) \
            acc[2*q+i][n] = __builtin_amdgcn_mfma_f32_16x16x32_bf16( \
                afr[i][ks], bfr[n][ks], acc[2*q+i][n], 0,0,0); \
      __builtin_amdgcn_s_setprio(0); \
      __builtin_amdgcn_s_barrier(); \
    } \
    if(kt + 1 < NT){ \
      if(kt + 2 < NT) asm volatile("s_waitcnt vmcnt(2)" ::: "memory"); \
      else            asm volatile("s_waitcnt vmcnt(0)" ::: "memory"); \
      __builtin_amdgcn_s_barrier(); \
    } \
  }

// ------- plain 256x256 8-phase GEMM ---------------------------------------
template<int EPI>
__global__ __launch_bounds__(512) void k_gemm256(
    const unsigned short* __restrict__ A, int lda,
    const unsigned short* __restrict__ Bt, int ldb,
    void* __restrict__ Cout, int ldc,
    const float* __restrict__ bias, const unsigned short* __restrict__ resid, int K)
{
  __shared__ __align__(16) unsigned short LA[2][256*64];
  __shared__ __align__(16) unsigned short LB[2][256*64];
  int tid = threadIdx.x;
  int lane = tid & 63;
  int lr = lane & 15, lg = lane >> 4;
  int w = tid >> 6, wr = w >> 2, wc = w & 3;
  int nwg = gridDim.x * gridDim.y;
  int v = xcd_swz(blockIdx.y * gridDim.x + blockIdx.x, nwg);
  int bx = v % gridDim.x, by = v / gridDim.x;
  int m0 = by * 256, n0 = bx * 256;
  int NT = K >> 6;

  f32x4 acc[8][4];
  #pragma unroll
  for(int m=0;m<8;m++)
    #pragma unroll
    for(int n=0;n<4;n++) acc[m][n] = (f32x4){0.f,0.f,0.f,0.f};

  GEMM256_BODY(A, Bt)

  #pragma unroll
  for(int m=0;m<8;m++){
    #pragma unroll
    for(int n=0;n<4;n++){
      int col = n0 + wc*64 + n*16 + lr;
      float bb = bias[col];
      #pragma unroll
      for(int r=0;r<4;r++){
        int row = m0 + wr*128 + m*16 + lg*4 + r;
        size_t o = (size_t)row*ldc + col;
        float v2 = acc[m][n][r] + bb;
        if constexpr (EPI == 0){
          ((unsigned short*)Cout)[o] = f2b(v2);
        } else if constexpr (EPI == 1){
          ((unsigned short*)Cout)[o] = f2b(v2 > 0.f ? v2 : 0.f);
        } else if constexpr (EPI == 2){
          ((unsigned short*)Cout)[o] = f2b(v2 + b2f(resid[o]));
        } else {
          ((float*)Cout)[o] = v2 + b2f(resid[o]);
        }
      }
    }
  }
}

// ------- 256x256 8-phase split GEMM: per-1024-col outputs; TSLOT -> Vt ----
template<int TSLOT>
__global__ __launch_bounds__(512) void k_gemmsplit256(
    const unsigned short* __restrict__ A,
    const unsigned short* __restrict__ A2, int lda,
    const unsigned short* __restrict__ Bt, int ldb,
    unsigned short* __restrict__ C0, unsigned short* __restrict__ C1,
    unsigned short* __restrict__ C2,
    const float* __restrict__ bias, int K)
{
  __shared__ __align__(16) unsigned short LA[2][256*64];
  __shared__ __align__(16) unsigned short LB[2][256*64];
  int tid = threadIdx.x;
  int lane = tid & 63;
  int lr = lane & 15, lg = lane >> 4;
  int w = tid >> 6, wr = w >> 2, wc = w & 3;
  int nwg = gridDim.x * gridDim.y;
  int v = xcd_swz(blockIdx.y * gridDim.x + blockIdx.x, nwg);
  int bx = v % gridDim.x, by = v / gridDim.x;
  int m0 = by * 256, n0 = bx * 256;
  int NT = K >> 6;
  int slot = bx >> 2;
  unsigned short* Cs = slot == 0 ? C0 : (slot == 1 ? C1 : C2);
  const unsigned short* Au = (slot == 0) ? A2 : A;
  int nl0 = (bx & 3) * 256;

  f32x4 acc[8][4];
  #pragma unroll
  for(int m=0;m<8;m++)
    #pragma unroll
    for(int n=0;n<4;n++) acc[m][n] = (f32x4){0.f,0.f,0.f,0.f};

  GEMM256_BODY(Au, Bt)

  if(slot != TSLOT){
    #pragma unroll
    for(int m=0;m<8;m++){
      #pragma unroll
      for(int n=0;n<4;n++){
        int coll = nl0 + wc*64 + n*16 + lr;
        float bb = bias[bx*256 + wc*64 + n*16 + lr];
        #pragma unroll
        for(int r=0;r<4;r++){
          int row = m0 + wr*128 + m*16 + lg*4 + r;
          Cs[(size_t)row*1024 + coll] = f2b(acc[m][n][r] + bb);
        }
      }
    }
  } else {
    #pragma unroll
    for(int m=0;m<8;m++){
      #pragma unroll
      for(int n=0;n<4;n++){
        int vcol = nl0 + wc*64 + n*16 + lr;
        float bb = bias[bx*256 + wc*64 + n*16 + lr];
        int rowb = m0 + wr*128 + m*16 + lg*4;
        int z = (rowb >> 9)*16 + (vcol >> 6);
        unsigned short tmp[4];
        #pragma unroll
        for(int r=0;r<4;r++) tmp[r] = f2b(acc[m][n][r] + bb);
        *(ushort4*)&Cs[((size_t)(z*64 + (vcol & 63)))*512 + (rowb & 511)] = *(ushort4*)tmp;
      }
    }
  }
}

// ------- 128x64 GEMM, double-buffered, XCD-swizzled -----------------------
template<int EPI>
__global__ __launch_bounds__(256) void k_gemm64(
    const unsigned short* __restrict__ A, int lda,
    const unsigned short* __restrict__ Bt, int ldb,
    void* __restrict__ Cout, int ldc,
    const float* __restrict__ bias, const unsigned short* __restrict__ resid, int K)
{
  __shared__ unsigned short As[2][128*32];
  __shared__ unsigned short Bs[2][64*32];
  int tid = threadIdx.x, lane = tid & 63, w = tid >> 6;
  int lr = lane & 15, lg = lane >> 4;
  int nwg = gridDim.x * gridDim.y;
  int v = xcd_swz(blockIdx.y * gridDim.x + blockIdx.x, nwg);
  int bx = v % gridDim.x, by = v / gridDim.x;
  int m0 = by * 128, n0 = bx * 64;

  f32x4 acc[2][4];
  #pragma unroll
  for(int m=0;m<2;m++)
    #pragma unroll
    for(int n=0;n<4;n++) acc[m][n] = (f32x4){0.f,0.f,0.f,0.f};

  #pragma unroll
  for(int j=0;j<2;j++){
    int idx = j*256 + tid;
    GLD16(A + (size_t)(m0 + (idx>>2))*lda + (idx&3)*8,
          As[0] + (size_t)(j*256 + (tid & 192))*8);
  }
  GLD16(Bt + (size_t)(n0 + (tid>>2))*ldb + (tid&3)*8,
        Bs[0] + (size_t)(tid & 192)*8);
  __syncthreads();

  int cur = 0;
  for(int k0 = 0; k0 < K; k0 += 32){
    if(k0 + 32 < K){
      #pragma unroll
      for(int j=0;j<2;j++){
        int idx = j*256 + tid;
        GLD16(A + (size_t)(m0 + (idx>>2))*lda + k0 + 32 + (idx&3)*8,
              As[cur^1] + (size_t)(j*256 + (tid & 192))*8);
      }
      GLD16(Bt + (size_t)(n0 + (tid>>2))*ldb + k0 + 32 + (tid&3)*8,
            Bs[cur^1] + (size_t)(tid & 192)*8);
    }
    bf16x8 a[2], bf[4];
    #pragma unroll
    for(int m=0;m<2;m++) a[m] = *(const bf16x8*)&As[cur][(w*32 + m*16 + lr)*32 + lg*8];
    #pragma unroll
    for(int n=0;n<4;n++) bf[n] = *(const bf16x8*)&Bs[cur][(n*16 + lr)*32 + lg*8];
    #pragma unroll
    for(int m=0;m<2;m++)
      #pragma unroll
      for(int n=0;n<4;n++)
        acc[m][n] = __builtin_amdgcn_mfma_f32_16x16x32_bf16(a[m], bf[n], acc[m][n], 0,0,0);
    __syncthreads();
    cur ^= 1;
  }

  #pragma unroll
  for(int m=0;m<2;m++){
    #pragma unroll
    for(int n=0;n<4;n++){
      int col = n0 + n*16 + lr;
      float bb = bias[col];
      #pragma unroll
      for(int r=0;r<4;r++){
        int row = m0 + w*32 + m*16 + lg*4 + r;
        size_t o = (size_t)row*ldc + col;
        float v2 = acc[m][n][r] + bb;
        if constexpr (EPI == 0){
          ((unsigned short*)Cout)[o] = f2b(v2);
        } else if constexpr (EPI == 1){
          ((unsigned short*)Cout)[o] = f2b(v2 > 0.f ? v2 : 0.f);
        } else if constexpr (EPI == 2){
          ((unsigned short*)Cout)[o] = f2b(v2 + b2f(resid[o]));
        } else {
          ((float*)Cout)[o] = v2 + b2f(resid[o]);
        }
      }
    }
  }
}

// -- fused attention (XCD-swizzled), K staged via LDS with XOR swizzle -----
// Grid must be (16,16,8). C may alias Q (Q consumed into regs first).
// col mapping: col = cb*64 + w*16 + lr  (all waves active in every K-chunk)
template<bool CAUSAL>
__global__ __launch_bounds__(256) void k_attnf(
    const unsigned short* Q,
    const unsigned short* __restrict__ Km,
    const unsigned short* __restrict__ Vt,
    float* __restrict__ P,
    unsigned short* C)
{
  int tid = threadIdx.x, lane = tid & 63, w = tid >> 6;
  int lr = lane & 15, lg = lane >> 4;
  int L = (blockIdx.z * 16 + blockIdx.y) * 16 + blockIdx.x;
  int v = xcd_swz(L, 2048);
  int s0 = (v & 15) * 32;
  int h = (v >> 4) & 15;
  int b = v >> 8;
  int z = b*16 + h;
  const unsigned short* Qb = Q + ((size_t)(b*512 + s0))*1024 + h*64;
  const unsigned short* Kb = Km + ((size_t)(b*512))*1024 + h*64;
  float* Pb = P + ((size_t)(z*512 + s0))*512;

  __shared__ unsigned short P_lds[32*520];   // aliased: first 16 KB = K-stage
  __shared__ float redm[32][4];
  __shared__ float reds[32][4];
  unsigned short* Ks = P_lds;                // K chunk [128 cols][64 k] swizzled

  bf16x8 aq[2][2];
  #pragma unroll
  for(int m=0;m<2;m++)
    #pragma unroll
    for(int kk=0;kk<2;kk++)
      aq[m][kk] = *(const bf16x8*)(Qb + (size_t)(m*16 + lr)*1024 + kk*32 + lg*8);

  f32x4 sc[2][8];
  #pragma unroll
  for(int m=0;m<2;m++)
    #pragma unroll
    for(int cb=0;cb<8;cb++) sc[m][cb] = (f32x4){0.f,0.f,0.f,0.f};

  // QK^T in 4 chunks of 128 K-columns, K staged in LDS
  for(int cc2 = 0; cc2 < 4; ++cc2){
    #pragma unroll
    for(int j=0;j<4;j++){
      int g = j*256 + tid;
      int s = g ^ ((g >> 3) & 7);
      GLD16(Kb + (size_t)(cc2*128 + (s>>3))*1024 + (s&7)*8,
            Ks + (size_t)g*8);
    }
    asm volatile("s_waitcnt vmcnt(0)" ::: "memory");
    __syncthreads();
    #pragma unroll
    for(int cbl=0;cbl<2;cbl++){
      int cb = cc2*2 + cbl;
      int col_l = cbl*64 + w*16 + lr;      // within-chunk column
      #pragma unroll
      for(int kk=0; kk<2; kk++){
        int ch = (col_l*8 + kk*4 + lg) ^ (col_l & 7);
        bf16x8 bq = *(const bf16x8*)(Ks + (size_t)ch*8);
        #pragma unroll
        for(int m=0;m<2;m++)
          sc[m][cb] = __builtin_amdgcn_mfma_f32_16x16x32_bf16(aq[m][kk], bq, sc[m][cb], 0,0,0);
      }
    }
    __syncthreads();
  }

  #pragma unroll
  for(int m=0;m<2;m++)
    #pragma unroll
    for(int cb=0;cb<8;cb++)
      #pragma unroll
      for(int r=0;r<4;r++){
        int row_l = m*16 + lg*4 + r;
        int col = cb*64 + w*16 + lr;
        float sv = sc[m][cb][r] * 0.125f;
        if(CAUSAL && col > s0 + row_l) sv = -1e9f;
        sc[m][cb][r] = sv;
      }

  float gmax[2][4];
  #pragma unroll
  for(int m=0;m<2;m++)
    #pragma unroll
    for(int r=0;r<4;r++){
      float pm = -1e30f;
      #pragma unroll
      for(int cb=0;cb<8;cb++) pm = fmaxf(pm, sc[m][cb][r]);
      #pragma unroll
      for(int off=1; off<16; off<<=1) pm = fmaxf(pm, __shfl_xor(pm, off));
      if(lr == 0) redm[m*16 + lg*4 + r][w] = pm;
    }
  __syncthreads();
  #pragma unroll
  for(int m=0;m<2;m++)
    #pragma unroll
    for(int r=0;r<4;r++){
      int row_l = m*16 + lg*4 + r;
      gmax[m][r] = fmaxf(fmaxf(redm[row_l][0], redm[row_l][1]),
                         fmaxf(redm[row_l][2], redm[row_l][3]));
    }
  #pragma unroll
  for(int m=0;m<2;m++)
    #pragma unroll
    for(int r=0;r<4;r++){
      float ps = 0.f;
      #pragma unroll
      for(int cb=0;cb<8;cb++){
        float e = __expf(sc[m][cb][r] - gmax[m][r]);
        sc[m][cb][r] = e;
        ps += e;
      }
      #pragma unroll
      for(int off=1; off<16; off<<=1) ps += __shfl_xor(ps, off);
      if(lr == 0) reds[m*16 + lg*4 + r][w] = ps;
    }
  __syncthreads();
  #pragma unroll
  for(int m=0;m<2;m++)
    #pragma unroll
    for(int r=0;r<4;r++){
      int row_l = m*16 + lg*4 + r;
      float inv = 1.f / (reds[row_l][0] + reds[row_l][1] + reds[row_l][2] + reds[row_l][3]);
      #pragma unroll
      for(int cb=0;cb<8;cb++){
        int col = cb*64 + w*16 + lr;
        float p = sc[m][cb][r] * inv;
        Pb[(size_t)row_l*512 + col] = p;
        P_lds[row_l*520 + col] = f2b(p);
      }
    }
  __syncthreads();

  const unsigned short* Vb = Vt + ((size_t)z*64 + w*16 + lr)*512;
  f32x4 pacc[2];
  pacc[0] = (f32x4){0.f,0.f,0.f,0.f};
  pacc[1] = (f32x4){0.f,0.f,0.f,0.f};
  for(int kk = 0; kk < 16; kk++){
    bf16x8 bfrag = *(const bf16x8*)(Vb + kk*32 + lg*8);
    #pragma unroll
    for(int m=0;m<2;m++){
      bf16x8 afrag = *(const bf16x8*)&P_lds[(m*16 + lr)*520 + kk*32 + lg*8];
      pacc[m] = __builtin_amdgcn_mfma_f32_16x16x32_bf16(afrag, bfrag, pacc[m], 0,0,0);
    }
  }
  #pragma unroll
  for(int m=0;m<2;m++)
    #pragma unroll
    for(int r=0;r<4;r++)
      C[((size_t)(b*512 + s0 + m*16 + lg*4 + r))*1024 + h*64 + w*16 + lr] = f2b(pacc[m][r]);
}

// ------- LayerNorm over D=1024; templated in/out dtype (0=bf16,1=f32) -----
template<int F32IN, int F32OUT>
__global__ __launch_bounds__(256) void k_ln(const void* __restrict__ in,
    const float* __restrict__ g, const float* __restrict__ be,
    void* __restrict__ out)
{
  int row = blockIdx.x, tid = threadIdx.x;
  float v[4];
  if constexpr (F32IN){
    f32x4 u = *(const f32x4*)((const float*)in + (size_t)row*1024 + tid*4);
    v[0]=u[0]; v[1]=u[1]; v[2]=u[2]; v[3]=u[3];
  } else {
    uint2 u = *(const uint2*)((const unsigned short*)in + (size_t)row*1024 + tid*4);
    v[0] = b2f(u.x & 0xFFFF); v[1] = b2f(u.x >> 16);
    v[2] = b2f(u.y & 0xFFFF); v[3] = b2f(u.y >> 16);
  }
  float s = v[0]+v[1]+v[2]+v[3];
  float s2 = v[0]*v[0]+v[1]*v[1]+v[2]*v[2]+v[3]*v[3];
  #pragma unroll
  for(int off=1; off<64; off<<=1){ s += __shfl_xor(s, off); s2 += __shfl_xor(s2, off); }
  __shared__ float red[2][4];
  int w = tid >> 6;
  if((tid & 63) == 0){ red[0][w] = s; red[1][w] = s2; }
  __syncthreads();
  s  = red[0][0]+red[0][1]+red[0][2]+red[0][3];
  s2 = red[1][0]+red[1][1]+red[1][2]+red[1][3];
  float mu = s * (1.f/1024.f);
  float var = s2 * (1.f/1024.f) - mu*mu;
  float rstd = rsqrtf(var + 1e-6f);
  int c = tid*4;
  float y0 = (v[0]-mu)*rstd*g[c+0] + be[c+0];
  float y1 = (v[1]-mu)*rstd*g[c+1] + be[c+1];
  float y2 = (v[2]-mu)*rstd*g[c+2] + be[c+2];
  float y3 = (v[3]-mu)*rstd*g[c+3] + be[c+3];
  if constexpr (F32OUT){
    f32x4 o = {y0, y1, y2, y3};
    *(f32x4*)((float*)out + (size_t)row*1024 + c) = o;
  } else {
    unsigned int o0 = (unsigned int)f2b(y0) | ((unsigned int)f2b(y1) << 16);
    unsigned int o1 = (unsigned int)f2b(y2) | ((unsigned int)f2b(y3) << 16);
    *(uint2*)((unsigned short*)out + (size_t)row*1024 + c) = make_uint2(o0, o1);
  }
}

// ---------------- launch ---------------------------------------------------
extern "C" void kernel_launch(void* const* d_in, const int* in_sizes, int n_in,
                              void* d_out, int out_size, void* d_ws, size_t ws_size,
                              hipStream_t stream)
{
  float* out0 = (float*)d_out;

  static const int exp_sizes[29] = {
    4194304, 4194304, 262144,
    1048576, 1024, 1048576, 1024, 1048576, 1024, 1048576, 1024,
    1048576, 1024, 1048576, 1024, 1048576, 1024, 1048576, 1024,
    1024, 1024, 1024, 1024, 1024, 1024,
    4194304, 4096, 4194304, 1024 };
  bool ok = (n_in == 29);
  if(ok) for(int i=0;i<29;i++) if(in_sizes[i] != exp_sizes[i]) { ok = false; break; }
  if(!ok){
    k_fill<<<2048,256,0,stream>>>(out0, (long long)out_size, 100.0f);
    return;
  }
  size_t nslots = ws_size > 131072 ? (ws_size - 131072) / 8388608 : 0;
  if(nslots < 5){
    k_fill<<<2048,256,0,stream>>>(out0, (long long)out_size, 200.0f);
    return;
  }
  bool bigws = nslots >= 9;

  const void* g1f = d_in[19];
  char* ws = (char*)d_ws;
  float* bias = (float*)(ws);
  unsigned short* SL[9];
  for(int i=0;i<9;i++) SL[i] = (unsigned short*)(ws + 131072 + (size_t)i*8388608);

  float* P1 = out0 + 4194304;
  float* P2 = P1 + 33554432;
  unsigned short* Q2buf = (unsigned short*)out0;

  SmallConv scv;
  const int si[16] = {4,6,8,10,12,14,16,18,19,20,21,22,23,24,26,28};
  const int sn[16] = {1024,1024,1024,1024,1024,1024,1024,1024,
                      1024,1024,1024,1024,1024,1024,4096,1024};
  const int so[16] = {0,1024,2048,3072,4096,5120,6144,7168,
                      8192,9216,10240,11264,12288,13312,14336,18432};
  for(int i=0;i<16;i++){ scv.src[i]=d_in[si[i]]; scv.n[i]=sn[i]; scv.off[i]=so[i]; }

  // ---- MHA1 (self, causal) ----
  {
    TW4 tw{}; tw.s[0]=d_in[3]; tw.s[1]=d_in[5]; tw.s[2]=d_in[7]; tw.s[3]=d_in[9];
    k_prepA<true><<<6160,256,0,stream>>>(scv, bias, d_in[0], SL[0], tw, SL[1], g1f);
  }
  k_gemmsplit256<2><<<dim3(12,16),512,0,stream>>>(SL[0], SL[0],1024, SL[1],1024,
                                                  SL[2], SL[3], SL[4], bias+0, 1024);
  k_attnf<true><<<dim3(16,16,8),256,0,stream>>>(SL[2], SL[3], SL[4], P1, SL[2]);
  k_gemm64<2><<<dim3(16,32),256,0,stream>>>(SL[2],1024, SL[1]+3145728,1024,
                                            SL[3],1024, bias+3072, SL[0], 1024);
  k_ln<0,0><<<4096,256,0,stream>>>(SL[3], bias+8192, bias+9216, SL[4]);

  // ---- MHA2 (cross, unmasked): merged Q2/K2/V2 ----
  {
    TW4 tw{}; tw.s[0]=d_in[11]; tw.s[1]=d_in[13]; tw.s[2]=d_in[15]; tw.s[3]=d_in[17];
    k_prepA<false><<<6144,256,0,stream>>>(scv, bias, d_in[1], SL[0], tw, SL[1], g1f);
  }
  k_gemmsplit256<2><<<dim3(12,16),512,0,stream>>>(SL[0], SL[4],1024, SL[1],1024,
                                                  Q2buf, SL[2], SL[3], bias+4096, 1024);
  k_attnf<false><<<dim3(16,16,8),256,0,stream>>>(Q2buf, SL[2], SL[3], P2, SL[0]);
  k_gemm64<2><<<dim3(16,32),256,0,stream>>>(SL[0],1024, SL[1]+3145728,1024,
                                            SL[2],1024, bias+7168, SL[4], 1024);
  k_ln<0,0><<<4096,256,0,stream>>>(SL[2], bias+10240, bias+11264, SL[3]);

  // ---- FFN ----
  k_prep3<<<8192,256,0,stream>>>(d_in[25], SL[4], d_in[27], SL[0], g1f);
  if(bigws){
    unsigned short* H = SL[5];
    k_gemm256<1><<<dim3(16,16),512,0,stream>>>(SL[3],1024, SL[4],1024, H,4096,
                                               bias+14336, nullptr, 1024);
    k_gemm64<3><<<dim3(16,32),256,0,stream>>>(H,4096, SL[0],4096, out0,1024, bias+18432, SL[3], 4096);
    k_ln<1,1><<<4096,256,0,stream>>>(out0, bias+12288, bias+13312, out0);
  } else {
    unsigned short* H = SL[1];
    for(int c=0;c<2;c++){
      unsigned short* arow = SL[3] + (size_t)c*2097152;
      float* orow = out0 + (size_t)c*2097152;
      k_gemm256<1><<<dim3(16,8),512,0,stream>>>(arow,1024, SL[4],1024, H,4096,
                                                bias+14336, nullptr, 1024);
      k_gemm64<3><<<dim3(16,16),256,0,stream>>>(H,4096, SL[0],4096, orow,1024, bias+18432, arow, 4096);
      k_ln<1,1><<<2048,256,0,stream>>>(orow, bias+12288, bias+13312, orow);
    }
  }
}